// Round 7
// baseline (282.519 us; speedup 1.0000x reference)
//
#include <hip/hip_runtime.h>
#include <hip/hip_bf16.h>

#define B_  4
#define T_  2048
#define D_  1024
#define H_  8
#define DH_ 128
#define TE_ 2048
#define M_  (B_*T_)   // 8192

using short8 = __attribute__((ext_vector_type(8))) short;
using f32x4  = __attribute__((ext_vector_type(4))) float;

__device__ __forceinline__ ushort f2bf(float f) {
  union { float f; unsigned u; } v; v.f = f;
  unsigned r = (v.u + 0x7fffu + ((v.u >> 16) & 1u)) >> 16;
  return (ushort)r;
}
__device__ __forceinline__ float bf2f(ushort h) {
  union { unsigned u; float f; } v; v.u = ((unsigned)h) << 16;
  return v.f;
}

// async global->LDS, 16B per lane. LDS dest = wave-uniform base + lane*16.
#define GLOAD_LDS16(g, l) __builtin_amdgcn_global_load_lds( \
    (const __attribute__((address_space(1))) void*)(g), \
    (__attribute__((address_space(3))) void*)(l), 16, 0, 0)

// ---------------------------------------------------------------------------
// 128x128 tile MFMA mainloop, BK=64 two-barrier structure (measured best:
// 633 TF on the qkv shape). NOTE (R6 lesson): this loop is latency-sensitive
// to the L2-residency of its inputs -- schedule the producer of A/B as the
// immediately-preceding dispatch where possible.
// ---------------------------------------------------------------------------
__device__ __forceinline__ void gemm_mainloop(
    const ushort* __restrict__ A, int lda,
    const ushort* __restrict__ Bt, int ldb,
    int K, ushort (*As)[128*32], ushort (*Bs)[128*32], f32x4 acc[4][4])
{
  const int tid  = threadIdx.x;
  const int lane = tid & 63;
  const int wave = tid >> 6;
  const int row  = tid >> 2;          // 0..63 (16 rows per wave per call)
  const int ck   = (tid & 3) * 8;     // 16B chunk within a 64B (k=32) row
  const int wm   = (wave & 1) * 64;
  const int wn   = (wave >> 1) * 64;
  const int fr   = lane & 15;
  const int quad = lane >> 4;

  const ushort* ga0 = A  + (size_t)row*lda + ck;
  const ushort* ga1 = A  + (size_t)(row+64)*lda + ck;
  const ushort* gb0 = Bt + (size_t)row*ldb + ck;
  const ushort* gb1 = Bt + (size_t)(row+64)*ldb + ck;
  const int woff = wave*512;

  for (int k0 = 0; k0 < K; k0 += 64) {
    GLOAD_LDS16(ga0 + k0,      As[0] + woff);
    GLOAD_LDS16(ga1 + k0,      As[0] + 2048 + woff);
    GLOAD_LDS16(gb0 + k0,      Bs[0] + woff);
    GLOAD_LDS16(gb1 + k0,      Bs[0] + 2048 + woff);
    GLOAD_LDS16(ga0 + k0 + 32, As[1] + woff);
    GLOAD_LDS16(ga1 + k0 + 32, As[1] + 2048 + woff);
    GLOAD_LDS16(gb0 + k0 + 32, Bs[1] + woff);
    GLOAD_LDS16(gb1 + k0 + 32, Bs[1] + 2048 + woff);
    __syncthreads();   // drains vmcnt before fragment reads
    short8 af[2][4], bw[2][4];
#pragma unroll
    for (int c = 0; c < 2; ++c)
#pragma unroll
      for (int i = 0; i < 4; ++i) {
        af[c][i] = *(const short8*)&As[c][(wm + i*16 + fr)*32 + quad*8];
        bw[c][i] = *(const short8*)&Bs[c][(wn + i*16 + fr)*32 + quad*8];
      }
#pragma unroll
    for (int c = 0; c < 2; ++c)
#pragma unroll
      for (int i = 0; i < 4; ++i)
#pragma unroll
        for (int j = 0; j < 4; ++j)
          acc[i][j] = __builtin_amdgcn_mfma_f32_16x16x32_bf16(af[c][i], bw[c][j], acc[i][j], 0, 0, 0);
    __syncthreads();
  }
}

// ---------------------------------------------------------------------------
// QKV GEMM: xn[8192,1024] @ Wqkv_t[3072,1024]^T. n-tile (128) == one head.
// grp 0: q  -> fused softmax over dh (register/shuffle)
// grp 1: k  -> exp(v + bias + (1-mask)*-1e6) TRANSPOSED kT [B,H,dh,T]
//              (UNNORMALIZED); per-(b,h,d) sums atomicAdd into ksum.
// grp 2: v  -> (+bias)*mask, TRANSPOSED vT [B,H,dh,T]
// ---------------------------------------------------------------------------
__global__ __launch_bounds__(256) void gemm_qkv_kernel(
    const ushort* __restrict__ xn, const ushort* __restrict__ Wt,
    const float* __restrict__ bq, const float* __restrict__ bk,
    const float* __restrict__ bv, const float* __restrict__ mask,
    ushort* __restrict__ q, ushort* __restrict__ kT, ushort* __restrict__ vT,
    float* __restrict__ ksum)
{
  __shared__ __align__(16) ushort As[2][128*32], Bs[2][128*32];
  const int m0 = blockIdx.x * 128;
  const int nt = blockIdx.y;            // 0..23
  f32x4 acc[4][4] = {};
  gemm_mainloop(xn + (size_t)m0*D_, D_, Wt + (size_t)nt*128*D_, D_, D_, As, Bs, acc);

  const int tid = threadIdx.x;
  const int lane = tid & 63, wave = tid >> 6;
  const int wm = (wave & 1)*64, wn = (wave >> 1)*64;
  const int fr = lane & 15, quad = lane >> 4;
  const int grp = nt >> 3;              // 0=q 1=k 2=v
  const int h = nt & 7;
  const int hbase = h*DH_;

  if (grp == 0) {
    float* redm = (float*)As;        // [128][2]
    float* reds = (float*)As + 256;  // [128][2]
    const int wi = wn >> 6;
    float bb[4];
#pragma unroll
    for (int j = 0; j < 4; ++j) bb[j] = bq[hbase + wn + j*16 + fr];
#pragma unroll
    for (int i = 0; i < 4; ++i)
#pragma unroll
      for (int r = 0; r < 4; ++r) {
        float m = -1e30f;
#pragma unroll
        for (int j = 0; j < 4; ++j) m = fmaxf(m, acc[i][j][r] + bb[j]);
        m = fmaxf(m, __shfl_xor(m, 1, 64));
        m = fmaxf(m, __shfl_xor(m, 2, 64));
        m = fmaxf(m, __shfl_xor(m, 4, 64));
        m = fmaxf(m, __shfl_xor(m, 8, 64));
        if (fr == 0) redm[(wm + i*16 + quad*4 + r)*2 + wi] = m;
      }
    __syncthreads();
#pragma unroll
    for (int i = 0; i < 4; ++i)
#pragma unroll
      for (int r = 0; r < 4; ++r) {
        int R = wm + i*16 + quad*4 + r;
        float gm = fmaxf(redm[R*2], redm[R*2+1]);
        float s = 0.f;
#pragma unroll
        for (int j = 0; j < 4; ++j) {
          float e = __expf(acc[i][j][r] + bb[j] - gm);
          acc[i][j][r] = e; s += e;
        }
        s += __shfl_xor(s, 1, 64);
        s += __shfl_xor(s, 2, 64);
        s += __shfl_xor(s, 4, 64);
        s += __shfl_xor(s, 8, 64);
        if (fr == 0) reds[R*2 + wi] = s;
      }
    __syncthreads();
#pragma unroll
    for (int i = 0; i < 4; ++i)
#pragma unroll
      for (int r = 0; r < 4; ++r) {
        int R = wm + i*16 + quad*4 + r;
        float inv = 1.0f / (reds[R*2] + reds[R*2+1]);
        size_t m = (size_t)(m0 + R);
#pragma unroll
        for (int j = 0; j < 4; ++j)
          q[m*D_ + hbase + wn + j*16 + fr] = f2bf(acc[i][j][r] * inv);
      }
  } else {
    const float* bias = (grp == 1) ? bk : bv;
    ushort* dstT = (grp == 1) ? kT : vT;
    const int b = m0 >> 11;
    const int t_in_b = m0 & (T_-1);
#pragma unroll
    for (int j = 0; j < 4; ++j) {
      int col = wn + j*16 + fr;
      float bb = bias[hbase + col];
      float sj = 0.f;
#pragma unroll
      for (int i = 0; i < 4; ++i) {
        int t0 = t_in_b + wm + i*16 + quad*4;
        ushort4 pk; ushort* pp = (ushort*)&pk;
#pragma unroll
        for (int r = 0; r < 4; ++r) {
          int m = m0 + wm + i*16 + quad*4 + r;
          float v = acc[i][j][r] + bb;
          if (grp == 1) {
            v = __expf(v + (1.0f - mask[m]) * -1000000.0f);
            sj += v;
          } else {
            v *= mask[m];
          }
          pp[r] = f2bf(v);
        }
        *(ushort4*)&dstT[((size_t)(b*H_ + h)*DH_ + col)*T_ + t0] = pk;
      }
      if (grp == 1) {
        sj += __shfl_xor(sj, 16, 64);
        sj += __shfl_xor(sj, 32, 64);
        if (quad == 0) atomicAdd(&ksum[(b*H_ + h)*DH_ + col], sj);
      }
    }
  }
}

// att partials: split-K=8 over T (256 blocks). P[s][bh][l][d]
__global__ __launch_bounds__(256) void gemm_att_kernel(
    const ushort* __restrict__ kT, const ushort* __restrict__ vT,
    float* __restrict__ P)
{
  __shared__ __align__(16) ushort As[2][128*32], Bs[2][128*32];
  const int bh = blockIdx.x;
  const int s  = blockIdx.y;
  f32x4 acc[4][4] = {};
  gemm_mainloop(kT + (size_t)bh*DH_*T_ + s*256, T_,
                vT + (size_t)bh*DH_*T_ + s*256, T_, 256, As, Bs, acc);
  const int tid = threadIdx.x, lane = tid & 63, wave = tid >> 6;
  const int wm = (wave & 1)*64, wn = (wave >> 1)*64, fr = lane & 15, quad = lane >> 4;
  float* Pb = P + ((size_t)(s*32 + bh))*DH_*DH_;
#pragma unroll
  for (int i = 0; i < 4; ++i)
#pragma unroll
    for (int j = 0; j < 4; ++j) {
      int l = wn + j*16 + fr;
      int d0 = wm + i*16 + quad*4;
      float4 pk = {acc[i][j][0], acc[i][j][1], acc[i][j][2], acc[i][j][3]};
      *(float4*)&Pb[(size_t)l*DH_ + d0] = pk;   // attT[l][d]
    }
}

// reduce split-K partials, normalize rows by ksum[d] -> attT bf16
__global__ __launch_bounds__(256) void att_reduce_kernel(
    const float* __restrict__ P, const float* __restrict__ ksum,
    ushort* __restrict__ attT)
{
  const int e = (blockIdx.x*256 + threadIdx.x) * 4;
  float4 s = {0.f, 0.f, 0.f, 0.f};
#pragma unroll
  for (int k = 0; k < 8; ++k) {
    float4 p = *(const float4*)&P[(size_t)k*32*DH_*DH_ + e];
    s.x += p.x; s.y += p.y; s.z += p.z; s.w += p.w;
  }
  const int bh = e >> 14;          // 128*128 per bh page
  const int d  = e & 127;
  const float4 ks = *(const float4*)&ksum[bh*DH_ + d];
  ushort4 o; ushort* op = (ushort*)&o;
  op[0] = f2bf(s.x / ks.x); op[1] = f2bf(s.y / ks.y);
  op[2] = f2bf(s.z / ks.z); op[3] = f2bf(s.w / ks.w);
  *(ushort4*)&attT[e] = o;
}

// y = q @ att per (b,h,t-tile)
__global__ __launch_bounds__(256) void gemm_y_kernel(
    const ushort* __restrict__ q, const ushort* __restrict__ attT,
    ushort* __restrict__ y)
{
  __shared__ __align__(16) ushort As[2][128*32], Bs[2][128*32];
  const int mt = blockIdx.x;            // t-tile 0..15
  const int bh = blockIdx.y;            // 0..31
  const int b = bh >> 3, h = bh & 7;
  const int m0 = b*T_ + mt*128;
  f32x4 acc[4][4] = {};
  gemm_mainloop(q + (size_t)m0*D_ + h*DH_, D_,
                attT + (size_t)bh*DH_*DH_, DH_, DH_, As, Bs, acc);
  const int tid = threadIdx.x, lane = tid & 63, wave = tid >> 6;
  const int wm = (wave & 1)*64, wn = (wave >> 1)*64, fr = lane & 15, quad = lane >> 4;
#pragma unroll
  for (int i = 0; i < 4; ++i)
#pragma unroll
    for (int j = 0; j < 4; ++j) {
      int l = wn + j*16 + fr;
#pragma unroll
      for (int r = 0; r < 4; ++r) {
        int m = m0 + wm + i*16 + quad*4 + r;
        y[(size_t)m*D_ + h*DH_ + l] = f2bf(acc[i][j][r]);
      }
    }
}

// out = act @ WoutT + b_out + x   (fp32 store)
__global__ __launch_bounds__(256) void gemm_out_kernel(
    const ushort* __restrict__ act, const ushort* __restrict__ WoutT,
    const float* __restrict__ b_out, const float* __restrict__ x,
    float* __restrict__ out)
{
  __shared__ __align__(16) ushort As[2][128*32], Bs[2][128*32];
  const int m0 = blockIdx.x*128, n0 = blockIdx.y*128;
  f32x4 acc[4][4] = {};
  gemm_mainloop(act + (size_t)m0*D_, D_, WoutT + (size_t)n0*D_, D_, D_, As, Bs, acc);
  const int tid = threadIdx.x, lane = tid & 63, wave = tid >> 6;
  const int wm = (wave & 1)*64, wn = (wave >> 1)*64, fr = lane & 15, quad = lane >> 4;
#pragma unroll
  for (int i = 0; i < 4; ++i)
#pragma unroll
    for (int j = 0; j < 4; ++j) {
      int col = n0 + wn + j*16 + fr;
      float bb = b_out[col];
#pragma unroll
      for (int r = 0; r < 4; ++r) {
        int m = m0 + wm + i*16 + quad*4 + r;
        out[(size_t)m*D_ + col] = acc[i][j][r] + bb + x[(size_t)m*D_ + col];
      }
    }
}

// LN over D of x (fp32) -> xn (bf16). Launched LAST before gemm_qkv so xn
// is L2-hot (R6: breaking this order cost qkv 85->111 us).
__global__ __launch_bounds__(256) void ln1_kernel(
    const float* __restrict__ x, const float* __restrict__ w,
    const float* __restrict__ bb, ushort* __restrict__ xn)
{
  __shared__ float red[8];
  const int row = blockIdx.x, tid = threadIdx.x;
  const int lane = tid & 63, wave = tid >> 6;
  float4 v = *(const float4*)&x[(size_t)row*D_ + tid*4];
  float s  = v.x + v.y + v.z + v.w;
  float sq = v.x*v.x + v.y*v.y + v.z*v.z + v.w*v.w;
#pragma unroll
  for (int off = 32; off; off >>= 1) { s += __shfl_xor(s, off, 64); sq += __shfl_xor(sq, off, 64); }
  if (lane == 0) { red[wave] = s; red[4+wave] = sq; }
  __syncthreads();
  s  = red[0] + red[1] + red[2] + red[3];
  sq = red[4] + red[5] + red[6] + red[7];
  float mean = s * (1.0f/D_);
  float var  = sq * (1.0f/D_) - mean*mean;
  float rstd = rsqrtf(var + 1e-5f);
  int c = tid*4;
  float vv[4] = {v.x, v.y, v.z, v.w};
  ushort4 o; ushort* op = (ushort*)&o;
#pragma unroll
  for (int i = 0; i < 4; ++i) op[i] = f2bf((vv[i]-mean)*rstd*w[c+i] + bb[c+i]);
  *(ushort4*)&xn[(size_t)row*D_ + c] = o;
}

// LN2 + FiLM + SiLU: y(bf16) -> act(bf16)
__global__ __launch_bounds__(256) void ln2_film_kernel(
    const ushort* __restrict__ y, const float* __restrict__ w,
    const float* __restrict__ bb, const float* __restrict__ film,
    const float* __restrict__ b_emb, ushort* __restrict__ act)
{
  __shared__ float red[8];
  const int row = blockIdx.x, tid = threadIdx.x;
  const int lane = tid & 63, wave = tid >> 6;
  const int b = row >> 11;
  ushort4 raw = *(const ushort4*)&y[(size_t)row*D_ + tid*4];
  ushort* u = (ushort*)&raw;
  float v[4];
  float s = 0.f, sq = 0.f;
#pragma unroll
  for (int i = 0; i < 4; ++i) { v[i] = bf2f(u[i]); s += v[i]; sq += v[i]*v[i]; }
#pragma unroll
  for (int off = 32; off; off >>= 1) { s += __shfl_xor(s, off, 64); sq += __shfl_xor(sq, off, 64); }
  if (lane == 0) { red[wave] = s; red[4+wave] = sq; }
  __syncthreads();
  s  = red[0] + red[1] + red[2] + red[3];
  sq = red[4] + red[5] + red[6] + red[7];
  float mean = s * (1.0f/D_);
  float var  = sq * (1.0f/D_) - mean*mean;
  float rstd = rsqrtf(var + 1e-5f);
  int c = tid*4;
  ushort4 o; ushort* op = (ushort*)&o;
#pragma unroll
  for (int i = 0; i < 4; ++i) {
    float yn = (v[i]-mean)*rstd*w[c+i] + bb[c+i];
    float scale = film[b*2048 + c+i]        + b_emb[c+i];
    float shift = film[b*2048 + 1024 + c+i] + b_emb[1024 + c+i];
    float hh = yn*(1.f + scale) + shift;
    op[i] = f2bf(hh / (1.f + __expf(-hh)));
  }
  *(ushort4*)&act[(size_t)row*D_ + c] = o;
}

// film = silu(emb) @ W_emb, W_emb read once, shared across 4 batches.
__global__ __launch_bounds__(256) void film_kernel(
    const float* __restrict__ emb, const float* __restrict__ W_emb,
    float* __restrict__ film)
{
  __shared__ float se[4][64];
  const int tid = threadIdx.x;
  const int j  = blockIdx.x*256 + tid;
  const int t0 = blockIdx.y*64;
  { int b = tid >> 6, tt = tid & 63;
    float e = emb[b*TE_ + t0 + tt];
    se[b][tt] = e / (1.f + __expf(-e)); }
  __syncthreads();
  float a0 = 0.f, a1 = 0.f, a2 = 0.f, a3 = 0.f;
#pragma unroll 8
  for (int tt = 0; tt < 64; ++tt) {
    float wv = W_emb[(size_t)(t0 + tt)*2048 + j];
    a0 += se[0][tt]*wv; a1 += se[1][tt]*wv;
    a2 += se[2][tt]*wv; a3 += se[3][tt]*wv;
  }
  atomicAdd(&film[0*2048 + j], a0);
  atomicAdd(&film[1*2048 + j], a1);
  atomicAdd(&film[2*2048 + j], a2);
  atomicAdd(&film[3*2048 + j], a3);
}

// transpose+cast weights: Wq/Wk/Wv -> Wqkv_t[3*1024,1024] bf16; W_out -> WoutT
__global__ __launch_bounds__(256) void prep_w_kernel(
    const float* __restrict__ Wq, const float* __restrict__ Wk,
    const float* __restrict__ Wv, const float* __restrict__ Wout,
    ushort* __restrict__ Wqkvt, ushort* __restrict__ WoutT)
{
  __shared__ float tile[32][33];
  const int z = blockIdx.z;
  const float* S = (z == 0) ? Wq : (z == 1) ? Wk : (z == 2) ? Wv : Wout;
  ushort* Dst = (z < 3) ? (Wqkvt + (size_t)z*D_*D_) : WoutT;
  const int n0 = blockIdx.x*32, k0 = blockIdx.y*32;
  const int tx = threadIdx.x & 31, ty = threadIdx.x >> 5;
#pragma unroll
  for (int i = 0; i < 4; ++i)
    tile[ty + i*8][tx] = S[(size_t)(k0 + ty + i*8)*D_ + n0 + tx];
  __syncthreads();
#pragma unroll
  for (int i = 0; i < 4; ++i)
    Dst[(size_t)(n0 + ty + i*8)*D_ + k0 + tx] = f2bf(tile[tx][ty + i*8]);
}

extern "C" void kernel_launch(void* const* d_in, const int* in_sizes, int n_in,
                              void* d_out, int out_size, void* d_ws, size_t ws_size,
                              hipStream_t stream)
{
  const float* x     = (const float*)d_in[0];
  const float* emb   = (const float*)d_in[1];
  const float* mask  = (const float*)d_in[2];
  const float* ln_w  = (const float*)d_in[4];
  const float* ln_b  = (const float*)d_in[5];
  const float* Wq    = (const float*)d_in[6];
  const float* bq    = (const float*)d_in[7];
  const float* Wk    = (const float*)d_in[8];
  const float* bk    = (const float*)d_in[9];
  const float* Wv    = (const float*)d_in[10];
  const float* bv    = (const float*)d_in[11];
  const float* W_emb = (const float*)d_in[12];
  const float* b_emb = (const float*)d_in[13];
  const float* ln2_w = (const float*)d_in[14];
  const float* ln2_b = (const float*)d_in[15];
  const float* Wout  = (const float*)d_in[16];
  const float* b_out = (const float*)d_in[17];
  float* out = (float*)d_out;

  char* ws = (char*)d_ws;
  size_t off = 0;
  auto alloc = [&](size_t bytes) { void* p = ws + off; off += (bytes + 255) & ~size_t(255); return p; };
  ushort* xn    = (ushort*)alloc((size_t)M_*D_*2);
  ushort* q     = (ushort*)alloc((size_t)M_*D_*2);
  ushort* kT    = (ushort*)alloc((size_t)M_*D_*2);
  ushort* vT    = (ushort*)alloc((size_t)M_*D_*2);
  ushort* y     = (ushort*)alloc((size_t)M_*D_*2);
  ushort* Wqkvt = (ushort*)alloc((size_t)3*D_*D_*2);
  ushort* WoutT = (ushort*)alloc((size_t)D_*D_*2);
  ushort* attT  = (ushort*)alloc((size_t)B_*H_*DH_*DH_*2);
  float*  film  = (float*)alloc((size_t)B_*2*D_*4);        // 32 KB
  float*  ksum  = (float*)alloc((size_t)B_*H_*DH_*4);      // 16 KB, right after film
  ushort* act   = xn;            // xn dead once act is produced
  float*  P     = (float*)y;     // split-K partials (16.8 MB) alias y

  hipMemsetAsync(film, 0, (size_t)(B_*2*D_ + B_*H_*DH_)*4, stream);  // film + ksum
  // Order matters (R6 lesson): ln1 runs LAST so xn is L2-hot for gemm_qkv.
  film_kernel<<<dim3(8, 32), 256, 0, stream>>>(emb, W_emb, film);
  prep_w_kernel<<<dim3(32, 32, 4), 256, 0, stream>>>(Wq, Wk, Wv, Wout, Wqkvt, WoutT);
  ln1_kernel<<<M_, 256, 0, stream>>>(x, ln_w, ln_b, xn);
  gemm_qkv_kernel<<<dim3(64, 24), 256, 0, stream>>>(xn, Wqkvt, bq, bk, bv, mask, q, kT, vT, ksum);
  gemm_att_kernel<<<dim3(32, 8), 256, 0, stream>>>(kT, vT, P);
  att_reduce_kernel<<<512, 256, 0, stream>>>(P, ksum, attT);
  gemm_y_kernel<<<dim3(16, 32), 256, 0, stream>>>(q, attT, y);
  ln2_film_kernel<<<M_, 256, 0, stream>>>(y, ln2_w, ln2_b, film, b_emb, act);
  gemm_out_kernel<<<dim3(64, 8), 256, 0, stream>>>(act, WoutT, b_out, x, out);
}

// Round 8
// 279.319 us; speedup vs baseline: 1.0115x; 1.0115x over previous
//
#include <hip/hip_runtime.h>
#include <hip/hip_bf16.h>

#define B_  4
#define T_  2048
#define D_  1024
#define H_  8
#define DH_ 128
#define TE_ 2048
#define M_  (B_*T_)   // 8192

using short8 = __attribute__((ext_vector_type(8))) short;
using f32x4  = __attribute__((ext_vector_type(4))) float;

__device__ __forceinline__ ushort f2bf(float f) {
  union { float f; unsigned u; } v; v.f = f;
  unsigned r = (v.u + 0x7fffu + ((v.u >> 16) & 1u)) >> 16;
  return (ushort)r;
}
__device__ __forceinline__ float bf2f(ushort h) {
  union { unsigned u; float f; } v; v.u = ((unsigned)h) << 16;
  return v.f;
}

// async global->LDS, 16B per lane. LDS dest = wave-uniform base + lane*16.
#define GLOAD_LDS16(g, l) __builtin_amdgcn_global_load_lds( \
    (const __attribute__((address_space(1))) void*)(g), \
    (__attribute__((address_space(3))) void*)(l), 16, 0, 0)

// ---------------------------------------------------------------------------
// 128x128 tile MFMA mainloop, BK=64 two-barrier structure (measured best:
// 633 TF on the qkv shape). R6/R7 lesson: latency-sensitive to L2-residency
// of A/B -- the producer of A must be the freshest writer before dispatch.
// ---------------------------------------------------------------------------
__device__ __forceinline__ void gemm_mainloop(
    const ushort* __restrict__ A, int lda,
    const ushort* __restrict__ Bt, int ldb,
    int K, ushort (*As)[128*32], ushort (*Bs)[128*32], f32x4 acc[4][4])
{
  const int tid  = threadIdx.x;
  const int lane = tid & 63;
  const int wave = tid >> 6;
  const int row  = tid >> 2;          // 0..63 (16 rows per wave per call)
  const int ck   = (tid & 3) * 8;     // 16B chunk within a 64B (k=32) row
  const int wm   = (wave & 1) * 64;
  const int wn   = (wave >> 1) * 64;
  const int fr   = lane & 15;
  const int quad = lane >> 4;

  const ushort* ga0 = A  + (size_t)row*lda + ck;
  const ushort* ga1 = A  + (size_t)(row+64)*lda + ck;
  const ushort* gb0 = Bt + (size_t)row*ldb + ck;
  const ushort* gb1 = Bt + (size_t)(row+64)*ldb + ck;
  const int woff = wave*512;

  for (int k0 = 0; k0 < K; k0 += 64) {
    GLOAD_LDS16(ga0 + k0,      As[0] + woff);
    GLOAD_LDS16(ga1 + k0,      As[0] + 2048 + woff);
    GLOAD_LDS16(gb0 + k0,      Bs[0] + woff);
    GLOAD_LDS16(gb1 + k0,      Bs[0] + 2048 + woff);
    GLOAD_LDS16(ga0 + k0 + 32, As[1] + woff);
    GLOAD_LDS16(ga1 + k0 + 32, As[1] + 2048 + woff);
    GLOAD_LDS16(gb0 + k0 + 32, Bs[1] + woff);
    GLOAD_LDS16(gb1 + k0 + 32, Bs[1] + 2048 + woff);
    __syncthreads();   // drains vmcnt before fragment reads
    short8 af[2][4], bw[2][4];
#pragma unroll
    for (int c = 0; c < 2; ++c)
#pragma unroll
      for (int i = 0; i < 4; ++i) {
        af[c][i] = *(const short8*)&As[c][(wm + i*16 + fr)*32 + quad*8];
        bw[c][i] = *(const short8*)&Bs[c][(wn + i*16 + fr)*32 + quad*8];
      }
#pragma unroll
    for (int c = 0; c < 2; ++c)
#pragma unroll
      for (int i = 0; i < 4; ++i)
#pragma unroll
        for (int j = 0; j < 4; ++j)
          acc[i][j] = __builtin_amdgcn_mfma_f32_16x16x32_bf16(af[c][i], bw[c][j], acc[i][j], 0, 0, 0);
    __syncthreads();
  }
}

// ---------------------------------------------------------------------------
// QKV GEMM: xn[8192,1024] @ Wqkv_t[3072,1024]^T. n-tile (128) == one head.
// grp 0: q  -> fused softmax over dh (register/shuffle)
// grp 1: k  -> exp(v + bias + (1-mask)*-1e6) TRANSPOSED kT [B,H,dh,T]
//              (UNNORMALIZED); per-(b,h,d) sums atomicAdd into ksum.
// grp 2: v  -> (+bias)*mask, TRANSPOSED vT [B,H,dh,T]
// ---------------------------------------------------------------------------
__global__ __launch_bounds__(256) void gemm_qkv_kernel(
    const ushort* __restrict__ xn, const ushort* __restrict__ Wt,
    const float* __restrict__ bq, const float* __restrict__ bk,
    const float* __restrict__ bv, const float* __restrict__ mask,
    ushort* __restrict__ q, ushort* __restrict__ kT, ushort* __restrict__ vT,
    float* __restrict__ ksum)
{
  __shared__ __align__(16) ushort As[2][128*32], Bs[2][128*32];
  const int m0 = blockIdx.x * 128;
  const int nt = blockIdx.y;            // 0..23
  f32x4 acc[4][4] = {};
  gemm_mainloop(xn + (size_t)m0*D_, D_, Wt + (size_t)nt*128*D_, D_, D_, As, Bs, acc);

  const int tid = threadIdx.x;
  const int lane = tid & 63, wave = tid >> 6;
  const int wm = (wave & 1)*64, wn = (wave >> 1)*64;
  const int fr = lane & 15, quad = lane >> 4;
  const int grp = nt >> 3;              // 0=q 1=k 2=v
  const int h = nt & 7;
  const int hbase = h*DH_;

  if (grp == 0) {
    float* redm = (float*)As;        // [128][2]
    float* reds = (float*)As + 256;  // [128][2]
    const int wi = wn >> 6;
    float bb[4];
#pragma unroll
    for (int j = 0; j < 4; ++j) bb[j] = bq[hbase + wn + j*16 + fr];
#pragma unroll
    for (int i = 0; i < 4; ++i)
#pragma unroll
      for (int r = 0; r < 4; ++r) {
        float m = -1e30f;
#pragma unroll
        for (int j = 0; j < 4; ++j) m = fmaxf(m, acc[i][j][r] + bb[j]);
        m = fmaxf(m, __shfl_xor(m, 1, 64));
        m = fmaxf(m, __shfl_xor(m, 2, 64));
        m = fmaxf(m, __shfl_xor(m, 4, 64));
        m = fmaxf(m, __shfl_xor(m, 8, 64));
        if (fr == 0) redm[(wm + i*16 + quad*4 + r)*2 + wi] = m;
      }
    __syncthreads();
#pragma unroll
    for (int i = 0; i < 4; ++i)
#pragma unroll
      for (int r = 0; r < 4; ++r) {
        int R = wm + i*16 + quad*4 + r;
        float gm = fmaxf(redm[R*2], redm[R*2+1]);
        float s = 0.f;
#pragma unroll
        for (int j = 0; j < 4; ++j) {
          float e = __expf(acc[i][j][r] + bb[j] - gm);
          acc[i][j][r] = e; s += e;
        }
        s += __shfl_xor(s, 1, 64);
        s += __shfl_xor(s, 2, 64);
        s += __shfl_xor(s, 4, 64);
        s += __shfl_xor(s, 8, 64);
        if (fr == 0) reds[R*2 + wi] = s;
      }
    __syncthreads();
#pragma unroll
    for (int i = 0; i < 4; ++i)
#pragma unroll
      for (int r = 0; r < 4; ++r) {
        int R = wm + i*16 + quad*4 + r;
        float inv = 1.0f / (reds[R*2] + reds[R*2+1]);
        size_t m = (size_t)(m0 + R);
#pragma unroll
        for (int j = 0; j < 4; ++j)
          q[m*D_ + hbase + wn + j*16 + fr] = f2bf(acc[i][j][r] * inv);
      }
  } else {
    const float* bias = (grp == 1) ? bk : bv;
    ushort* dstT = (grp == 1) ? kT : vT;
    const int b = m0 >> 11;
    const int t_in_b = m0 & (T_-1);
#pragma unroll
    for (int j = 0; j < 4; ++j) {
      int col = wn + j*16 + fr;
      float bb = bias[hbase + col];
      float sj = 0.f;
#pragma unroll
      for (int i = 0; i < 4; ++i) {
        int t0 = t_in_b + wm + i*16 + quad*4;
        ushort4 pk; ushort* pp = (ushort*)&pk;
#pragma unroll
        for (int r = 0; r < 4; ++r) {
          int m = m0 + wm + i*16 + quad*4 + r;
          float v = acc[i][j][r] + bb;
          if (grp == 1) {
            v = __expf(v + (1.0f - mask[m]) * -1000000.0f);
            sj += v;
          } else {
            v *= mask[m];
          }
          pp[r] = f2bf(v);
        }
        *(ushort4*)&dstT[((size_t)(b*H_ + h)*DH_ + col)*T_ + t0] = pk;
      }
      if (grp == 1) {
        sj += __shfl_xor(sj, 16, 64);
        sj += __shfl_xor(sj, 32, 64);
        if (quad == 0) atomicAdd(&ksum[(b*H_ + h)*DH_ + col], sj);
      }
    }
  }
}

// att partials: split-K=8 over T (256 blocks). P[s][bh][l][d]
__global__ __launch_bounds__(256) void gemm_att_kernel(
    const ushort* __restrict__ kT, const ushort* __restrict__ vT,
    float* __restrict__ P)
{
  __shared__ __align__(16) ushort As[2][128*32], Bs[2][128*32];
  const int bh = blockIdx.x;
  const int s  = blockIdx.y;
  f32x4 acc[4][4] = {};
  gemm_mainloop(kT + (size_t)bh*DH_*T_ + s*256, T_,
                vT + (size_t)bh*DH_*T_ + s*256, T_, 256, As, Bs, acc);
  const int tid = threadIdx.x, lane = tid & 63, wave = tid >> 6;
  const int wm = (wave & 1)*64, wn = (wave >> 1)*64, fr = lane & 15, quad = lane >> 4;
  float* Pb = P + ((size_t)(s*32 + bh))*DH_*DH_;
#pragma unroll
  for (int i = 0; i < 4; ++i)
#pragma unroll
    for (int j = 0; j < 4; ++j) {
      int l = wn + j*16 + fr;
      int d0 = wm + i*16 + quad*4;
      float4 pk = {acc[i][j][0], acc[i][j][1], acc[i][j][2], acc[i][j][3]};
      *(float4*)&Pb[(size_t)l*DH_ + d0] = pk;   // attT[l][d]
    }
}

// reduce split-K partials, normalize rows by ksum[d] -> attT bf16
__global__ __launch_bounds__(256) void att_reduce_kernel(
    const float* __restrict__ P, const float* __restrict__ ksum,
    ushort* __restrict__ attT)
{
  const int e = (blockIdx.x*256 + threadIdx.x) * 4;
  float4 s = {0.f, 0.f, 0.f, 0.f};
#pragma unroll
  for (int k = 0; k < 8; ++k) {
    float4 p = *(const float4*)&P[(size_t)k*32*DH_*DH_ + e];
    s.x += p.x; s.y += p.y; s.z += p.z; s.w += p.w;
  }
  const int bh = e >> 14;          // 128*128 per bh page
  const int d  = e & 127;
  const float4 ks = *(const float4*)&ksum[bh*DH_ + d];
  ushort4 o; ushort* op = (ushort*)&o;
  op[0] = f2bf(s.x / ks.x); op[1] = f2bf(s.y / ks.y);
  op[2] = f2bf(s.z / ks.z); op[3] = f2bf(s.w / ks.w);
  *(ushort4*)&attT[e] = o;
}

// y = q @ att per (b,h,t-tile)
__global__ __launch_bounds__(256) void gemm_y_kernel(
    const ushort* __restrict__ q, const ushort* __restrict__ attT,
    ushort* __restrict__ y)
{
  __shared__ __align__(16) ushort As[2][128*32], Bs[2][128*32];
  const int mt = blockIdx.x;            // t-tile 0..15
  const int bh = blockIdx.y;            // 0..31
  const int b = bh >> 3, h = bh & 7;
  const int m0 = b*T_ + mt*128;
  f32x4 acc[4][4] = {};
  gemm_mainloop(q + (size_t)m0*D_ + h*DH_, D_,
                attT + (size_t)bh*DH_*DH_, DH_, DH_, As, Bs, acc);
  const int tid = threadIdx.x, lane = tid & 63, wave = tid >> 6;
  const int wm = (wave & 1)*64, wn = (wave >> 1)*64, fr = lane & 15, quad = lane >> 4;
#pragma unroll
  for (int i = 0; i < 4; ++i)
#pragma unroll
    for (int j = 0; j < 4; ++j) {
      int l = wn + j*16 + fr;
#pragma unroll
      for (int r = 0; r < 4; ++r) {
        int m = m0 + wm + i*16 + quad*4 + r;
        y[(size_t)m*D_ + h*DH_ + l] = f2bf(acc[i][j][r]);
      }
    }
}

// out = act @ WoutT + b_out + x   (fp32 store)
__global__ __launch_bounds__(256) void gemm_out_kernel(
    const ushort* __restrict__ act, const ushort* __restrict__ WoutT,
    const float* __restrict__ b_out, const float* __restrict__ x,
    float* __restrict__ out)
{
  __shared__ __align__(16) ushort As[2][128*32], Bs[2][128*32];
  const int m0 = blockIdx.x*128, n0 = blockIdx.y*128;
  f32x4 acc[4][4] = {};
  gemm_mainloop(act + (size_t)m0*D_, D_, WoutT + (size_t)n0*D_, D_, D_, As, Bs, acc);
  const int tid = threadIdx.x, lane = tid & 63, wave = tid >> 6;
  const int wm = (wave & 1)*64, wn = (wave >> 1)*64, fr = lane & 15, quad = lane >> 4;
#pragma unroll
  for (int i = 0; i < 4; ++i)
#pragma unroll
    for (int j = 0; j < 4; ++j) {
      int col = n0 + wn + j*16 + fr;
      float bb = b_out[col];
#pragma unroll
      for (int r = 0; r < 4; ++r) {
        int m = m0 + wm + i*16 + quad*4 + r;
        out[(size_t)m*D_ + col] = acc[i][j][r] + bb + x[(size_t)m*D_ + col];
      }
    }
}

// LN2 + FiLM + SiLU: y(bf16) -> act(bf16)
__global__ __launch_bounds__(256) void ln2_film_kernel(
    const ushort* __restrict__ y, const float* __restrict__ w,
    const float* __restrict__ bb, const float* __restrict__ film,
    const float* __restrict__ b_emb, ushort* __restrict__ act)
{
  __shared__ float red[8];
  const int row = blockIdx.x, tid = threadIdx.x;
  const int lane = tid & 63, wave = tid >> 6;
  const int b = row >> 11;
  ushort4 raw = *(const ushort4*)&y[(size_t)row*D_ + tid*4];
  ushort* u = (ushort*)&raw;
  float v[4];
  float s = 0.f, sq = 0.f;
#pragma unroll
  for (int i = 0; i < 4; ++i) { v[i] = bf2f(u[i]); s += v[i]; sq += v[i]*v[i]; }
#pragma unroll
  for (int off = 32; off; off >>= 1) { s += __shfl_xor(s, off, 64); sq += __shfl_xor(sq, off, 64); }
  if (lane == 0) { red[wave] = s; red[4+wave] = sq; }
  __syncthreads();
  s  = red[0] + red[1] + red[2] + red[3];
  sq = red[4] + red[5] + red[6] + red[7];
  float mean = s * (1.0f/D_);
  float var  = sq * (1.0f/D_) - mean*mean;
  float rstd = rsqrtf(var + 1e-5f);
  int c = tid*4;
  ushort4 o; ushort* op = (ushort*)&o;
#pragma unroll
  for (int i = 0; i < 4; ++i) {
    float yn = (v[i]-mean)*rstd*w[c+i] + bb[c+i];
    float scale = film[b*2048 + c+i]        + b_emb[c+i];
    float shift = film[b*2048 + 1024 + c+i] + b_emb[1024 + c+i];
    float hh = yn*(1.f + scale) + shift;
    op[i] = f2bf(hh / (1.f + __expf(-hh)));
  }
  *(ushort4*)&act[(size_t)row*D_ + c] = o;
}

// ---------------------------------------------------------------------------
// Fused prologue, ORDERED so ln1 blocks dispatch LAST (R6+R7 lesson: blocks
// run roughly in blockIdx order; ln1's xn output must be the freshest data
// in L2 when gemm_qkv starts, else qkv regresses 85->111 us).
//   bid [0, 256)          : film = silu(emb) @ W_emb (atomicAdd)
//   bid [256, 4352)       : weight transpose+cast tile
//   bid [4352, 4352+8192) : ln1 row (x fp32 -> xn bf16)
// ---------------------------------------------------------------------------
__global__ __launch_bounds__(256) void prologue_kernel(
    const float* __restrict__ x, const float* __restrict__ lw,
    const float* __restrict__ lb, ushort* __restrict__ xn,
    const float* __restrict__ Wq, const float* __restrict__ Wk,
    const float* __restrict__ Wv, const float* __restrict__ Wout,
    ushort* __restrict__ Wqkvt, ushort* __restrict__ WoutT,
    const float* __restrict__ emb, const float* __restrict__ W_emb,
    float* __restrict__ film)
{
  __shared__ float smem[32*33];
  const int bid = blockIdx.x;
  const int tid = threadIdx.x;

  if (bid < 256) {
    // ---- film: W_emb read once, shared across 4 batches ----
    const int j  = (bid & 7)*256 + tid;
    const int t0 = (bid >> 3)*64;
    float (*se)[64] = (float(*)[64])smem;
    { int b = tid >> 6, tt = tid & 63;
      float e = emb[b*TE_ + t0 + tt];
      se[b][tt] = e / (1.f + __expf(-e)); }
    __syncthreads();
    float a0 = 0.f, a1 = 0.f, a2 = 0.f, a3 = 0.f;
#pragma unroll 8
    for (int tt = 0; tt < 64; ++tt) {
      float wv = W_emb[(size_t)(t0 + tt)*2048 + j];
      a0 += se[0][tt]*wv; a1 += se[1][tt]*wv;
      a2 += se[2][tt]*wv; a3 += se[3][tt]*wv;
    }
    atomicAdd(&film[0*2048 + j], a0);
    atomicAdd(&film[1*2048 + j], a1);
    atomicAdd(&film[2*2048 + j], a2);
    atomicAdd(&film[3*2048 + j], a3);
  } else if (bid < 4352) {
    // ---- weight transpose+cast, 32x32 tile ----
    const int idx = bid - 256;
    const int z = idx >> 10;
    const int rem = idx & 1023;
    const int n0 = (rem & 31)*32, k0 = (rem >> 5)*32;
    const float* S = (z == 0) ? Wq : (z == 1) ? Wk : (z == 2) ? Wv : Wout;
    ushort* Dst = (z < 3) ? (Wqkvt + (size_t)z*D_*D_) : WoutT;
    float (*tile)[33] = (float(*)[33])smem;
    const int tx = tid & 31, ty = tid >> 5;
#pragma unroll
    for (int i = 0; i < 4; ++i)
      tile[ty + i*8][tx] = S[(size_t)(k0 + ty + i*8)*D_ + n0 + tx];
    __syncthreads();
#pragma unroll
    for (int i = 0; i < 4; ++i)
      Dst[(size_t)(n0 + ty + i*8)*D_ + k0 + tx] = f2bf(tile[tx][ty + i*8]);
  } else {
    // ---- ln1 (LAST: keeps xn L2-hot for gemm_qkv) ----
    const int row = bid - 4352;
    const int lane = tid & 63, wave = tid >> 6;
    float* red = smem;
    float4 v = *(const float4*)&x[(size_t)row*D_ + tid*4];
    float s  = v.x + v.y + v.z + v.w;
    float sq = v.x*v.x + v.y*v.y + v.z*v.z + v.w*v.w;
#pragma unroll
    for (int off = 32; off; off >>= 1) { s += __shfl_xor(s, off, 64); sq += __shfl_xor(sq, off, 64); }
    if (lane == 0) { red[wave] = s; red[4+wave] = sq; }
    __syncthreads();
    s  = red[0] + red[1] + red[2] + red[3];
    sq = red[4] + red[5] + red[6] + red[7];
    float mean = s * (1.0f/D_);
    float var  = sq * (1.0f/D_) - mean*mean;
    float rstd = rsqrtf(var + 1e-5f);
    int c = tid*4;
    float vv[4] = {v.x, v.y, v.z, v.w};
    ushort4 o; ushort* op = (ushort*)&o;
#pragma unroll
    for (int i = 0; i < 4; ++i) op[i] = f2bf((vv[i]-mean)*rstd*lw[c+i] + lb[c+i]);
    *(ushort4*)&xn[(size_t)row*D_ + c] = o;
  }
}

extern "C" void kernel_launch(void* const* d_in, const int* in_sizes, int n_in,
                              void* d_out, int out_size, void* d_ws, size_t ws_size,
                              hipStream_t stream)
{
  const float* x     = (const float*)d_in[0];
  const float* emb   = (const float*)d_in[1];
  const float* mask  = (const float*)d_in[2];
  const float* ln_w  = (const float*)d_in[4];
  const float* ln_b  = (const float*)d_in[5];
  const float* Wq    = (const float*)d_in[6];
  const float* bq    = (const float*)d_in[7];
  const float* Wk    = (const float*)d_in[8];
  const float* bk    = (const float*)d_in[9];
  const float* Wv    = (const float*)d_in[10];
  const float* bv    = (const float*)d_in[11];
  const float* W_emb = (const float*)d_in[12];
  const float* b_emb = (const float*)d_in[13];
  const float* ln2_w = (const float*)d_in[14];
  const float* ln2_b = (const float*)d_in[15];
  const float* Wout  = (const float*)d_in[16];
  const float* b_out = (const float*)d_in[17];
  float* out = (float*)d_out;

  char* ws = (char*)d_ws;
  size_t off = 0;
  auto alloc = [&](size_t bytes) { void* p = ws + off; off += (bytes + 255) & ~size_t(255); return p; };
  ushort* xn    = (ushort*)alloc((size_t)M_*D_*2);
  ushort* q     = (ushort*)alloc((size_t)M_*D_*2);
  ushort* kT    = (ushort*)alloc((size_t)M_*D_*2);
  ushort* vT    = (ushort*)alloc((size_t)M_*D_*2);
  ushort* y     = (ushort*)alloc((size_t)M_*D_*2);
  ushort* Wqkvt = (ushort*)alloc((size_t)3*D_*D_*2);
  ushort* WoutT = (ushort*)alloc((size_t)D_*D_*2);
  ushort* attT  = (ushort*)alloc((size_t)B_*H_*DH_*DH_*2);
  float*  film  = (float*)alloc((size_t)B_*2*D_*4);        // 32 KB
  float*  ksum  = (float*)alloc((size_t)B_*H_*DH_*4);      // 16 KB, right after film
  ushort* act   = xn;            // xn dead once act is produced
  float*  P     = (float*)y;     // split-K partials (16.8 MB) alias y

  hipMemsetAsync(film, 0, (size_t)(B_*2*D_ + B_*H_*DH_)*4, stream);  // film + ksum
  prologue_kernel<<<256 + 4096 + M_, 256, 0, stream>>>(
      x, ln_w, ln_b, xn, Wq, Wk, Wv, Wout, Wqkvt, WoutT, emb, W_emb, film);
  gemm_qkv_kernel<<<dim3(64, 24), 256, 0, stream>>>(xn, Wqkvt, bq, bk, bv, mask, q, kT, vT, ksum);
  gemm_att_kernel<<<dim3(32, 8), 256, 0, stream>>>(kT, vT, P);
  att_reduce_kernel<<<512, 256, 0, stream>>>(P, ksum, attT);
  gemm_y_kernel<<<dim3(16, 32), 256, 0, stream>>>(q, attT, y);
  ln2_film_kernel<<<M_, 256, 0, stream>>>(y, ln2_w, ln2_b, film, b_emb, act);
  gemm_out_kernel<<<dim3(64, 8), 256, 0, stream>>>(act, WoutT, b_out, x, out);
}